// Round 1
// baseline (215.772 us; speedup 1.0000x reference)
//
#include <hip/hip_runtime.h>
#include <stdint.h>

typedef int v4i __attribute__((ext_vector_type(4)));

// xt layout: [n][hp=58][wp=66][ci=128] int8, zero-padded (hp-1,wp-1 are src coords)
#define XT_H_STRIDE (66*128)          // 8448
#define XT_N_STRIDE (58*66*128)       // 489984
#define XT_BYTES    (32*58*66*128)    // 15,679,488
#define WQ_BYTES    (256*1152)        // 294,912

__device__ __forceinline__ void gload16(const void* g, void* l) {
  __builtin_amdgcn_global_load_lds(
      (const __attribute__((address_space(1))) void*)g,
      (__attribute__((address_space(3))) void*)l, 16, 0, 0);
}

// ---------------- x transform: fp32 NCHW -> int8 [n][hp][wp][ci] ----------------
__global__ __launch_bounds__(256) void xform_x(const float* __restrict__ x,
                                               char* __restrict__ xt) {
  int bid = blockIdx.x;         // 32*58 blocks
  int n  = bid / 58;
  int hp = bid - n * 58;
  int t = threadIdx.x;
  int srch = hp - 1;
  bool rowok = (srch >= 0) && (srch < 56);
  int srchc = rowok ? srch : 0;
  char* dstrow = xt + (size_t)n * XT_N_STRIDE + (size_t)hp * XT_H_STRIDE;
  const float* srcbase = x + (size_t)n * 128 * 3136 + (size_t)srchc * 56;
  for (int c = t; c < 528; c += 256) {   // 528 chunks of 16B = 66*128 bytes
    int cio = c / 66;                    // ci chunk 0..7
    int wp  = c - cio * 66;              // 0..65
    int srw = wp - 1;
    bool ok = rowok && (srw >= 0) && (srw < 56);
    int srwc = ok ? srw : 0;
    union { signed char b[16]; v4i v; } u;
#pragma unroll
    for (int j = 0; j < 16; ++j) {
      int ci = cio * 16 + j;
      float f = ok ? srcbase[(size_t)ci * 3136 + srwc] : 0.0f;
      u.b[j] = (signed char)(int)f;      // trunc, values in [-128,127]
    }
    *(v4i*)(dstrow + wp * 128 + cio * 16) = u.v;
  }
}

// ---------------- w transform: OIHW fp32 -> int8 [co][(kh*3+kw)*128+ci]; + scale ----------------
__global__ __launch_bounds__(256) void xform_w(const float* __restrict__ wsrc,
                                               const int* __restrict__ Aq,
                                               const int* __restrict__ Nq,
                                               char* __restrict__ wq,
                                               float* __restrict__ scale) {
  int idx = blockIdx.x * 256 + threadIdx.x;    // 1152 blocks -> 294912
  int co = idx / 1152;
  int r  = idx - co * 1152;
  int g  = r >> 7;            // kh*3+kw
  int ci = r & 127;
  int kh = g / 3;
  int kw = g - 3 * kh;
  float f = wsrc[(size_t)(co * 128 + ci) * 9 + kh * 3 + kw];
  wq[idx] = (signed char)(int)f;
  if (idx < 256) {
    scale[idx] = (float)Aq[idx] * exp2f(-(float)Nq[idx]);   // exact: A < 2^15
  }
}

// ---------------- GEMM: C[co][n,h,w] = sum_k wq[co][k] * xt[...] ----------------
// 128x128 tile, 4 waves (2x2), each wave 4x4 frags of mfma_i32_16x16x64_i8, BK=64.
__global__ __launch_bounds__(256) void qconv_gemm(
    const char* __restrict__ xt, const char* __restrict__ wq,
    const float* __restrict__ bias, const float* __restrict__ scale,
    const int* __restrict__ pmin, const int* __restrict__ pmax,
    float* __restrict__ out) {
  __shared__ __align__(16) char As[8192];   // [m=128][kk=64]
  __shared__ __align__(16) char Bs[8192];   // [s=128][kk=64]

  int bid = blockIdx.x;        // 1792
  int mt = bid & 1;            // M-tiles adjacent -> B-tile L2 reuse
  int nt = bid >> 1;           // 0..895
  int n  = nt / 28;
  int ht = nt - n * 28;
  int h0 = ht * 2;
  int m0 = mt * 128;

  int t  = threadIdx.x;
  int wv = t >> 6;
  int ln = t & 63;
  int quad = ln >> 4;
  int l16  = ln & 15;
  int wm = wv & 1, wn = wv >> 1;

  const char* wbase = wq + (size_t)m0 * 1152;
  const char* xbase = xt + (size_t)n * XT_N_STRIDE + (size_t)h0 * XT_H_STRIDE;

  // staging: chunk c in [0,512): LDS offset c*16; c1 = t (lds base wv*1024), c2 = t+256 (+4096)
  int a_m1 = t >> 2;                 // A row for c1 (c2: +64)
  int a_p  = (t & 3) * 16;           // 16B piece
  int b_w1 = t >> 2;                 // B: c1 -> dh=0, w = c>>2 ; c2 -> dh=1, w same
  char* asd1 = As + wv * 1024;
  char* asd2 = As + 4096 + wv * 1024;
  char* bsd1 = Bs + wv * 1024;
  char* bsd2 = Bs + 4096 + wv * 1024;

  v4i acc[4][4];
#pragma unroll
  for (int i = 0; i < 4; ++i)
#pragma unroll
    for (int j = 0; j < 4; ++j) {
      v4i z = {0, 0, 0, 0};
      acc[i][j] = z;
    }

  for (int kt = 0; kt < 18; ++kt) {
    int g  = kt >> 1;
    int c0 = (kt & 1) << 6;          // ci base within 128-group
    int kh = g / 3;
    int kw = g - 3 * kh;
    int k0 = kt << 6;

    if (kt) __syncthreads();

    // A tile: rows m0+[0,128), bytes [k0, k0+64)
    gload16(wbase + (size_t)a_m1 * 1152 + k0 + a_p, asd1);
    gload16(wbase + (size_t)(a_m1 + 64) * 1152 + k0 + a_p, asd2);
    // B tile: s in [0,128): row hp = h0 + (s>>6) + kh, wp = (s&63)+kw, ci = c0 + kk
    {
      const char* rowb = xbase + (size_t)kh * XT_H_STRIDE + (size_t)kw * 128 + c0;
      gload16(rowb + (size_t)b_w1 * 128 + a_p, bsd1);
      gload16(rowb + XT_H_STRIDE + (size_t)b_w1 * 128 + a_p, bsd2);
    }
    __syncthreads();

    v4i a[4], b[4];
#pragma unroll
    for (int i = 0; i < 4; ++i)
      a[i] = *(const v4i*)(As + (wm * 64 + i * 16 + l16) * 64 + quad * 16);
#pragma unroll
    for (int j = 0; j < 4; ++j)
      b[j] = *(const v4i*)(Bs + (wn * 64 + j * 16 + l16) * 64 + quad * 16);
#pragma unroll
    for (int i = 0; i < 4; ++i)
#pragma unroll
      for (int j = 0; j < 4; ++j)
        acc[i][j] = __builtin_amdgcn_mfma_i32_16x16x64_i8(a[i], b[j], acc[i][j], 0, 0, 0);
  }

  // epilogue: C row = co = m0 + wm*64 + i*16 + quad*4 + r ; col = spatial = wn*64 + j*16 + l16
  float mn = (float)pmin[0];
  float mx = (float)pmax[0];
#pragma unroll
  for (int i = 0; i < 4; ++i) {
    int co_b = m0 + wm * 64 + i * 16 + quad * 4;
#pragma unroll
    for (int r = 0; r < 4; ++r) {
      int co = co_b + r;
      float bs = bias[co];
      float sc = scale[co];
#pragma unroll
      for (int j = 0; j < 4; ++j) {
        int sl = wn * 64 + j * 16 + l16;
        int w  = sl & 63;
        int dh = sl >> 6;
        if (w < 56) {
          float f = (float)acc[i][j][r] + bs;
          f = rintf(f * sc);                 // half-to-even, matches np.round
          f = fminf(fmaxf(f, mn), mx);
          out[(((size_t)n * 256 + co) * 56 + (h0 + dh)) * 56 + w] = f;
        }
      }
    }
  }
}

extern "C" void kernel_launch(void* const* d_in, const int* in_sizes, int n_in,
                              void* d_out, int out_size, void* d_ws, size_t ws_size,
                              hipStream_t stream) {
  const float* x  = (const float*)d_in[0];
  const float* w  = (const float*)d_in[1];
  const float* b  = (const float*)d_in[2];
  const int*   Aq = (const int*)d_in[3];
  const int*   Nq = (const int*)d_in[4];
  const int*   mn = (const int*)d_in[5];
  const int*   mx = (const int*)d_in[6];
  float* out = (float*)d_out;

  char*  xt    = (char*)d_ws;                  // 15,679,488 B
  char*  wq    = xt + XT_BYTES;                // 294,912 B
  float* scale = (float*)(wq + WQ_BYTES);      // 1 KiB   (total ~16 MB of ws)

  hipLaunchKernelGGL(xform_x, dim3(32 * 58), dim3(256), 0, stream, x, xt);
  hipLaunchKernelGGL(xform_w, dim3(1152), dim3(256), 0, stream, w, Aq, Nq, wq, scale);
  hipLaunchKernelGGL(qconv_gemm, dim3(1792), dim3(256), 0, stream,
                     xt, wq, b, scale, mn, mx, out);
}

// Round 2
// 206.430 us; speedup vs baseline: 1.0453x; 1.0453x over previous
//
#include <hip/hip_runtime.h>
#include <stdint.h>

typedef int v4i __attribute__((ext_vector_type(4)));

// xt layout: [n][hp=58][wp=66][ci=128] int8, zero-padded (hp-1,wp-1 are src coords)
#define XT_H_STRIDE (66*128)          // 8448
#define XT_N_STRIDE (58*66*128)       // 489984
#define XT_BYTES    (32*58*66*128)    // 15,679,488
#define WQ_BYTES    (256*1152)        // 294,912

__device__ __forceinline__ void gload16(const void* g, void* l) {
  __builtin_amdgcn_global_load_lds(
      (const __attribute__((address_space(1))) void*)g,
      (__attribute__((address_space(3))) void*)l, 16, 0, 0);
}

// ---------------- x transform: fp32 NCHW -> int8 [n][hp][wp][ci] ----------------
// Lane mapping chosen for coalesced 16B writes: chunk c -> (wp = c>>3, cio = c&7),
// write addr = c*16 (lane-consecutive). Reads hit a 28KB/block region -> L1.
__global__ __launch_bounds__(256) void xform_x(const float* __restrict__ x,
                                               char* __restrict__ xt) {
  int bid = blockIdx.x;         // 32*58 blocks
  int n  = bid / 58;
  int hp = bid - n * 58;
  int t = threadIdx.x;
  int srch = hp - 1;
  bool rowok = (srch >= 0) && (srch < 56);
  int srchc = rowok ? srch : 0;
  char* dstrow = xt + (size_t)n * XT_N_STRIDE + (size_t)hp * XT_H_STRIDE;
  const float* srcbase = x + (size_t)n * 128 * 3136 + (size_t)srchc * 56;
  for (int c = t; c < 528; c += 256) {   // 528 chunks of 16B = 66*128 bytes
    int wp  = c >> 3;                    // 0..65
    int cio = c & 7;                     // ci chunk 0..7
    int srw = wp - 1;
    bool ok = rowok && (srw >= 0) && (srw < 56);
    int srwc = ok ? srw : 0;
    union { signed char b[16]; v4i v; } u;
#pragma unroll
    for (int j = 0; j < 16; ++j) {
      int ci = cio * 16 + j;
      float f = ok ? srcbase[(size_t)ci * 3136 + srwc] : 0.0f;
      u.b[j] = (signed char)(int)f;      // trunc, values in [-128,127]
    }
    *(v4i*)(dstrow + c * 16) = u.v;      // coalesced: consecutive lanes -> consecutive 16B
  }
}

// ---------------- w transform: OIHW fp32 -> int8 [co][(kh*3+kw)*128+ci]; + scale ----------------
__global__ __launch_bounds__(256) void xform_w(const float* __restrict__ wsrc,
                                               const int* __restrict__ Aq,
                                               const int* __restrict__ Nq,
                                               char* __restrict__ wq,
                                               float* __restrict__ scale) {
  int idx = blockIdx.x * 256 + threadIdx.x;    // 1152 blocks -> 294912
  int co = idx / 1152;
  int r  = idx - co * 1152;
  int g  = r >> 7;            // kh*3+kw
  int ci = r & 127;
  int kh = g / 3;
  int kw = g - 3 * kh;
  float f = wsrc[(size_t)(co * 128 + ci) * 9 + kh * 3 + kw];
  wq[idx] = (signed char)(int)f;
  if (idx < 256) {
    scale[idx] = (float)Aq[idx] * exp2f(-(float)Nq[idx]);   // exact: A < 2^15
  }
}

// ---------------- GEMM: C[co][n,h,w] = sum_k wq[co][k] * xt[...] ----------------
// 128x128 tile, 4 waves (2x2), each wave 4x4 frags of mfma_i32_16x16x64_i8, BK=64.
// LDS chunk XOR-swizzle: logical (row, piece q) stored at chunk slot c = q ^ ((row>>1)&3).
// Applied at staging via the *global* source offset (global_load_lds pins LDS slot = lane*16);
// read side picks chunk quad ^ ((l16>>1)&3). Kills the 8-way bank conflict (-> 2-way = free).
__global__ __launch_bounds__(256) void qconv_gemm(
    const char* __restrict__ xt, const char* __restrict__ wq,
    const float* __restrict__ bias, const float* __restrict__ scale,
    const int* __restrict__ pmin, const int* __restrict__ pmax,
    float* __restrict__ out) {
  __shared__ __align__(16) char As[8192];   // [m=128][kk=64]
  __shared__ __align__(16) char Bs[8192];   // [s=128][kk=64]

  int bid = blockIdx.x;        // 1792
  int mt = bid & 1;            // M-tiles adjacent -> B-tile L2 reuse
  int nt = bid >> 1;           // 0..895
  int n  = nt / 28;
  int ht = nt - n * 28;
  int h0 = ht * 2;
  int m0 = mt * 128;

  int t  = threadIdx.x;
  int wv = t >> 6;
  int ln = t & 63;
  int quad = ln >> 4;
  int l16  = ln & 15;
  int wm = wv & 1, wn = wv >> 1;

  const char* wbase = wq + (size_t)m0 * 1152;
  const char* xbase = xt + (size_t)n * XT_N_STRIDE + (size_t)h0 * XT_H_STRIDE;

  // staging: LDS slot t holds (row = t>>2, chunk slot c = t&3) -> fetch global piece
  // q = c ^ ((row>>1)&3) = (t&3) ^ ((t>>3)&3). Second loads (+64 rows) keep the same
  // swizzle since 64>>1 = 32 == 0 (mod 4).
  int a_m1 = t >> 2;                 // A row for slot t (second load: +64)
  int a_p  = (((t & 3) ^ ((t >> 3) & 3)) * 16);   // swizzled 16B piece
  int b_w1 = t >> 2;
  char* asd1 = As + wv * 1024;
  char* asd2 = As + 4096 + wv * 1024;
  char* bsd1 = Bs + wv * 1024;
  char* bsd2 = Bs + 4096 + wv * 1024;

  v4i acc[4][4];
#pragma unroll
  for (int i = 0; i < 4; ++i)
#pragma unroll
    for (int j = 0; j < 4; ++j) {
      v4i z = {0, 0, 0, 0};
      acc[i][j] = z;
    }

  int sw = (l16 >> 1) & 3;           // read-side swizzle term (base rows are mult of 16)
  int ca = (quad ^ sw) * 16;         // swizzled chunk byte offset within a 64B row

  for (int kt = 0; kt < 18; ++kt) {
    int g  = kt >> 1;
    int c0 = (kt & 1) << 6;          // ci base within 128-group
    int kh = g / 3;
    int kw = g - 3 * kh;
    int k0 = kt << 6;

    if (kt) __syncthreads();

    // A tile: rows m0+[0,128), bytes [k0, k0+64)
    gload16(wbase + (size_t)a_m1 * 1152 + k0 + a_p, asd1);
    gload16(wbase + (size_t)(a_m1 + 64) * 1152 + k0 + a_p, asd2);
    // B tile: s in [0,128): row hp = h0 + (s>>6) + kh, wp = (s&63)+kw, ci = c0 + kk
    {
      const char* rowb = xbase + (size_t)kh * XT_H_STRIDE + (size_t)kw * 128 + c0;
      gload16(rowb + (size_t)b_w1 * 128 + a_p, bsd1);
      gload16(rowb + XT_H_STRIDE + (size_t)b_w1 * 128 + a_p, bsd2);
    }
    __syncthreads();

    v4i a[4], b[4];
#pragma unroll
    for (int i = 0; i < 4; ++i)
      a[i] = *(const v4i*)(As + (wm * 64 + i * 16 + l16) * 64 + ca);
#pragma unroll
    for (int j = 0; j < 4; ++j)
      b[j] = *(const v4i*)(Bs + (wn * 64 + j * 16 + l16) * 64 + ca);
#pragma unroll
    for (int i = 0; i < 4; ++i)
#pragma unroll
      for (int j = 0; j < 4; ++j)
        acc[i][j] = __builtin_amdgcn_mfma_i32_16x16x64_i8(a[i], b[j], acc[i][j], 0, 0, 0);
  }

  // epilogue: C row = co = m0 + wm*64 + i*16 + quad*4 + r ; col = spatial = wn*64 + j*16 + l16
  float mn = (float)pmin[0];
  float mx = (float)pmax[0];
#pragma unroll
  for (int i = 0; i < 4; ++i) {
    int co_b = m0 + wm * 64 + i * 16 + quad * 4;
#pragma unroll
    for (int r = 0; r < 4; ++r) {
      int co = co_b + r;
      float bs = bias[co];
      float sc = scale[co];
#pragma unroll
      for (int j = 0; j < 4; ++j) {
        int sl = wn * 64 + j * 16 + l16;
        int w  = sl & 63;
        int dh = sl >> 6;
        if (w < 56) {
          float f = (float)acc[i][j][r] + bs;
          f = rintf(f * sc);                 // half-to-even, matches np.round
          f = fminf(fmaxf(f, mn), mx);
          out[(((size_t)n * 256 + co) * 56 + (h0 + dh)) * 56 + w] = f;
        }
      }
    }
  }
}

extern "C" void kernel_launch(void* const* d_in, const int* in_sizes, int n_in,
                              void* d_out, int out_size, void* d_ws, size_t ws_size,
                              hipStream_t stream) {
  const float* x  = (const float*)d_in[0];
  const float* w  = (const float*)d_in[1];
  const float* b  = (const float*)d_in[2];
  const int*   Aq = (const int*)d_in[3];
  const int*   Nq = (const int*)d_in[4];
  const int*   mn = (const int*)d_in[5];
  const int*   mx = (const int*)d_in[6];
  float* out = (float*)d_out;

  char*  xt    = (char*)d_ws;                  // 15,679,488 B
  char*  wq    = xt + XT_BYTES;                // 294,912 B
  float* scale = (float*)(wq + WQ_BYTES);      // 1 KiB   (total ~16 MB of ws)

  hipLaunchKernelGGL(xform_x, dim3(32 * 58), dim3(256), 0, stream, x, xt);
  hipLaunchKernelGGL(xform_w, dim3(1152), dim3(256), 0, stream, w, Aq, Nq, wq, scale);
  hipLaunchKernelGGL(qconv_gemm, dim3(1792), dim3(256), 0, stream,
                     xt, wq, b, scale, mn, mx, out);
}

// Round 3
// 195.626 us; speedup vs baseline: 1.1030x; 1.0552x over previous
//
#include <hip/hip_runtime.h>
#include <stdint.h>

typedef int   v4i __attribute__((ext_vector_type(4)));
typedef float v4f __attribute__((ext_vector_type(4)));

// xt layout: [n][hp=58][wp=66][ci=128] int8, zero-padded (hp-1,wp-1 are src coords)
#define XT_H_STRIDE (66*128)          // 8448
#define XT_N_STRIDE (58*66*128)       // 489984
#define XT_BYTES    (32*58*66*128)    // 15,679,488
#define WQ_BYTES    (256*1152)        // 294,912

__device__ __forceinline__ void gload16(const void* g, void* l) {
  __builtin_amdgcn_global_load_lds(
      (const __attribute__((address_space(1))) void*)g,
      (__attribute__((address_space(3))) void*)l, 16, 0, 0);
}

// ---------------- x transform: fp32 NCHW -> int8 [n][hp][wp][ci] ----------------
// Coalesced both sides via LDS transpose:
//   phase1: lane=w float4 reads (contiguous 224B per ci row), pack 4 ci-bytes -> dword,
//           ds_write_b32 into LB[w][ci/4] with 33-dword row stride (2-way banks = free)
//   phase2: lane-consecutive 16B chunk writes, 4x ds_read_b32 each (2-way banks)
__global__ __launch_bounds__(256) void xform_x(const float* __restrict__ x,
                                               char* __restrict__ xt) {
  __shared__ int LB[56 * 33];          // [w=0..55][32 ci-dwords + 1 pad] = 7392 B
  int bid = blockIdx.x;                // 32*58
  int n  = bid / 58;
  int hp = bid - n * 58;
  int t  = threadIdx.x;
  int srch = hp - 1;
  bool rowok = (srch >= 0) && (srch < 56);
  char* dstrow = xt + (size_t)n * XT_N_STRIDE + (size_t)hp * XT_H_STRIDE;

  if (rowok) {
    const float* rb = x + ((size_t)(n * 128) * 56 + srch) * 56;   // + ci*3136 + w
#pragma unroll
    for (int u0 = 0; u0 < 2; ++u0) {
      int u  = t + u0 * 256;
      int wb = u & 15;                 // w0 = wb*4
      int cb = u >> 4;                 // ci0 = cb*4, cb in [0,32)
      int w0 = wb * 4, ci0 = cb * 4;
      if (w0 < 56) {                   // rows >=56 never read by phase2
        int dw[4] = {0, 0, 0, 0};
#pragma unroll
        for (int i = 0; i < 4; ++i) {
          v4f f = *(const v4f*)(rb + (size_t)(ci0 + i) * 3136 + w0);
#pragma unroll
          for (int j = 0; j < 4; ++j)
            dw[j] |= (((int)f[j]) & 255) << (8 * i);   // byte k of dword = ci0+k
        }
#pragma unroll
        for (int j = 0; j < 4; ++j)
          LB[(w0 + j) * 33 + cb] = dw[j];
      }
    }
    __syncthreads();
    for (int c = t; c < 528; c += 256) {   // 16B chunks: wp = c>>3, cio = c&7
      int wp  = c >> 3;
      int cio = c & 7;
      int srw = wp - 1;
      v4i v = {0, 0, 0, 0};
      if (srw >= 0 && srw < 56) {
#pragma unroll
        for (int k = 0; k < 4; ++k) v[k] = LB[srw * 33 + cio * 4 + k];
      }
      *(v4i*)(dstrow + c * 16) = v;        // coalesced 1KB/wave
    }
  } else {
    v4i z = {0, 0, 0, 0};
    for (int c = t; c < 528; c += 256) *(v4i*)(dstrow + c * 16) = z;
  }
}

// ---------------- w transform: OIHW fp32 -> int8 [co][(kh*3+kw)*128+ci]; + scale ----------------
__global__ __launch_bounds__(256) void xform_w(const float* __restrict__ wsrc,
                                               const int* __restrict__ Aq,
                                               const int* __restrict__ Nq,
                                               char* __restrict__ wq,
                                               float* __restrict__ scale) {
  int idx = blockIdx.x * 256 + threadIdx.x;    // 1152 blocks -> 294912
  int co = idx / 1152;
  int r  = idx - co * 1152;
  int g  = r >> 7;
  int ci = r & 127;
  int kh = g / 3;
  int kw = g - 3 * kh;
  float f = wsrc[(size_t)(co * 128 + ci) * 9 + kh * 3 + kw];
  wq[idx] = (signed char)(int)f;
  if (idx < 256) {
    scale[idx] = (float)Aq[idx] * exp2f(-(float)Nq[idx]);   // exact: A < 2^15
  }
}

// ---------------- GEMM: C[co][n,h,w] = sum_k wq[co][k] * xt[...] ----------------
// 128x128 tile, 4 waves (2x2), 4x4 frags of mfma_i32_16x16x64_i8, BK=64.
// Software pipeline (m139-style): double-buffered LDS, raw s_barrier + s_waitcnt vmcnt(4)
// inline asm so kt+1's global_load_lds stay in flight across the barrier (the compiler's
// __syncthreads would drain vmcnt(0) and expose full load latency every kt).
// LDS chunk XOR-swizzle (staging source offset a_p / read side ca) keeps bank conflicts at 0.
__global__ __launch_bounds__(256) void qconv_gemm(
    const char* __restrict__ xt, const char* __restrict__ wq,
    const float* __restrict__ bias, const float* __restrict__ scale,
    const int* __restrict__ pmin, const int* __restrict__ pmax,
    float* __restrict__ out) {
  __shared__ __align__(16) char As[2][8192];   // [buf][m=128][kk=64]
  __shared__ __align__(16) char Bs[2][8192];   // [buf][s=128][kk=64]

  // XCD-aware swizzle: mt pair (shared B tile) + contiguous nt range per XCD.
  int bid = blockIdx.x;        // 1792
  int xcd = bid & 7;
  int q   = bid >> 3;          // 0..223
  int mt  = q & 1;
  int nt  = xcd * 112 + (q >> 1);   // 0..895
  int n   = nt / 28;
  int ht  = nt - n * 28;
  int h0  = ht * 2;
  int m0  = mt * 128;

  int t  = threadIdx.x;
  int wv = t >> 6;
  int ln = t & 63;
  int quad = ln >> 4;
  int l16  = ln & 15;
  int wm = wv & 1, wn = wv >> 1;

  const char* wbase = wq + (size_t)m0 * 1152;
  const char* xbase = xt + (size_t)n * XT_N_STRIDE + (size_t)h0 * XT_H_STRIDE;

  int a_m1 = t >> 2;
  int a_p  = (((t & 3) ^ ((t >> 3) & 3)) * 16);   // XOR-swizzled 16B source piece
  int b_w1 = t >> 2;
  int ldsoff = wv * 1024;

  v4i acc[4][4];
#pragma unroll
  for (int i = 0; i < 4; ++i)
#pragma unroll
    for (int j = 0; j < 4; ++j) {
      v4i z = {0, 0, 0, 0};
      acc[i][j] = z;
    }

  int sw = (l16 >> 1) & 3;
  int ca = (quad ^ sw) * 16;

  auto stage = [&](int kt, int p) {
    int g  = kt >> 1;
    int c0 = (kt & 1) << 6;
    int kh = g / 3;
    int kw = g - 3 * kh;
    int k0 = kt << 6;
    gload16(wbase + (size_t)a_m1 * 1152 + k0 + a_p, &As[p][ldsoff]);
    gload16(wbase + (size_t)(a_m1 + 64) * 1152 + k0 + a_p, &As[p][4096 + ldsoff]);
    const char* rowb = xbase + (size_t)kh * XT_H_STRIDE + (size_t)kw * 128 + c0;
    gload16(rowb + (size_t)b_w1 * 128 + a_p, &Bs[p][ldsoff]);
    gload16(rowb + XT_H_STRIDE + (size_t)b_w1 * 128 + a_p, &Bs[p][4096 + ldsoff]);
  };

  stage(0, 0);
  for (int kt = 0; kt < 18; ++kt) {
    int p = kt & 1;
    // B0: all waves done reading buf[1-p] (their ds_reads drained before their mfmas)
    asm volatile("s_barrier" ::: "memory");
    if (kt < 17) {
      stage(kt + 1, 1 - p);
      asm volatile("s_waitcnt vmcnt(4)" ::: "memory");   // oldest 4 (buf p) landed
    } else {
      asm volatile("s_waitcnt vmcnt(0)" ::: "memory");
    }
    // B1: every wave's buf-p loads landed
    asm volatile("s_barrier" ::: "memory");

    v4i a[4], b[4];
#pragma unroll
    for (int i = 0; i < 4; ++i)
      a[i] = *(const v4i*)(&As[p][(wm * 64 + i * 16 + l16) * 64 + ca]);
#pragma unroll
    for (int j = 0; j < 4; ++j)
      b[j] = *(const v4i*)(&Bs[p][(wn * 64 + j * 16 + l16) * 64 + ca]);
#pragma unroll
    for (int i = 0; i < 4; ++i)
#pragma unroll
      for (int j = 0; j < 4; ++j)
        acc[i][j] = __builtin_amdgcn_mfma_i32_16x16x64_i8(a[i], b[j], acc[i][j], 0, 0, 0);
  }

  // epilogue: co = m0 + wm*64 + i*16 + quad*4 + r ; spatial = wn*64 + j*16 + l16
  float mn = (float)pmin[0];
  float mx = (float)pmax[0];
#pragma unroll
  for (int i = 0; i < 4; ++i) {
    int co_b = m0 + wm * 64 + i * 16 + quad * 4;
#pragma unroll
    for (int r = 0; r < 4; ++r) {
      int co = co_b + r;
      float bs = bias[co];
      float sc = scale[co];
#pragma unroll
      for (int j = 0; j < 4; ++j) {
        int sl = wn * 64 + j * 16 + l16;
        int w  = sl & 63;
        int dh = sl >> 6;
        if (w < 56) {
          float f = (float)acc[i][j][r] + bs;
          f = rintf(f * sc);                 // half-to-even, matches np.round
          f = fminf(fmaxf(f, mn), mx);
          out[(((size_t)n * 256 + co) * 56 + (h0 + dh)) * 56 + w] = f;
        }
      }
    }
  }
}

extern "C" void kernel_launch(void* const* d_in, const int* in_sizes, int n_in,
                              void* d_out, int out_size, void* d_ws, size_t ws_size,
                              hipStream_t stream) {
  const float* x  = (const float*)d_in[0];
  const float* w  = (const float*)d_in[1];
  const float* b  = (const float*)d_in[2];
  const int*   Aq = (const int*)d_in[3];
  const int*   Nq = (const int*)d_in[4];
  const int*   mn = (const int*)d_in[5];
  const int*   mx = (const int*)d_in[6];
  float* out = (float*)d_out;

  char*  xt    = (char*)d_ws;                  // 15,679,488 B
  char*  wq    = xt + XT_BYTES;                // 294,912 B
  float* scale = (float*)(wq + WQ_BYTES);      // 1 KiB

  hipLaunchKernelGGL(xform_x, dim3(32 * 58), dim3(256), 0, stream, x, xt);
  hipLaunchKernelGGL(xform_w, dim3(1152), dim3(256), 0, stream, w, Aq, Nq, wq, scale);
  hipLaunchKernelGGL(qconv_gemm, dim3(1792), dim3(256), 0, stream,
                     xt, wq, b, scale, mn, mx, out);
}

// Round 4
// 190.197 us; speedup vs baseline: 1.1345x; 1.0285x over previous
//
#include <hip/hip_runtime.h>
#include <stdint.h>

typedef int   v4i __attribute__((ext_vector_type(4)));
typedef float v4f __attribute__((ext_vector_type(4)));

// xt layout: [n][hp=58][wp=66][ci=128] int8, zero-padded (hp-1,wp-1 are src coords)
#define XT_H_STRIDE (66*128)          // 8448
#define XT_N_STRIDE (58*66*128)       // 489984
#define XT_BYTES    (32*58*66*128)    // 15,679,488
#define WQ_BYTES    (256*1152)        // 294,912

__device__ __forceinline__ void gload16(const void* g, void* l) {
  __builtin_amdgcn_global_load_lds(
      (const __attribute__((address_space(1))) void*)g,
      (__attribute__((address_space(3))) void*)l, 16, 0, 0);
}

// ---------------- x transform: fp32 NCHW -> int8 [n][hp][wp][ci] ----------------
// Coalesced both sides via LDS transpose (see R3 notes).
__global__ __launch_bounds__(256) void xform_x(const float* __restrict__ x,
                                               char* __restrict__ xt) {
  __shared__ int LB[56 * 33];          // [w][32 ci-dwords + 1 pad]
  int bid = blockIdx.x;                // 32*58
  int n  = bid / 58;
  int hp = bid - n * 58;
  int t  = threadIdx.x;
  int srch = hp - 1;
  bool rowok = (srch >= 0) && (srch < 56);
  char* dstrow = xt + (size_t)n * XT_N_STRIDE + (size_t)hp * XT_H_STRIDE;

  if (rowok) {
    const float* rb = x + ((size_t)(n * 128) * 56 + srch) * 56;   // + ci*3136 + w
#pragma unroll
    for (int u0 = 0; u0 < 2; ++u0) {
      int u  = t + u0 * 256;
      int wb = u & 15;
      int cb = u >> 4;
      int w0 = wb * 4, ci0 = cb * 4;
      if (w0 < 56) {
        int dw[4] = {0, 0, 0, 0};
#pragma unroll
        for (int i = 0; i < 4; ++i) {
          v4f f = *(const v4f*)(rb + (size_t)(ci0 + i) * 3136 + w0);
#pragma unroll
          for (int j = 0; j < 4; ++j)
            dw[j] |= (((int)f[j]) & 255) << (8 * i);
        }
#pragma unroll
        for (int j = 0; j < 4; ++j)
          LB[(w0 + j) * 33 + cb] = dw[j];
      }
    }
    __syncthreads();
    for (int c = t; c < 528; c += 256) {
      int wp  = c >> 3;
      int cio = c & 7;
      int srw = wp - 1;
      v4i v = {0, 0, 0, 0};
      if (srw >= 0 && srw < 56) {
#pragma unroll
        for (int k = 0; k < 4; ++k) v[k] = LB[srw * 33 + cio * 4 + k];
      }
      *(v4i*)(dstrow + c * 16) = v;
    }
  } else {
    v4i z = {0, 0, 0, 0};
    for (int c = t; c < 528; c += 256) *(v4i*)(dstrow + c * 16) = z;
  }
}

// ---------------- w transform: OIHW fp32 -> int8 wq2[kt][co][64]; + scale ----------------
// GEMM-tile layout: per kt the 256x64 A panel is contiguous (8KB per 128-co half),
// so A staging is one contiguous 1KB read per wave.
__global__ __launch_bounds__(256) void xform_w(const float* __restrict__ wsrc,
                                               const int* __restrict__ Aq,
                                               const int* __restrict__ Nq,
                                               char* __restrict__ wq2,
                                               float* __restrict__ scale) {
  int idx = blockIdx.x * 256 + threadIdx.x;    // 294912
  int co = idx / 1152;
  int k  = idx - co * 1152;          // K index: g*128 + ci
  int g  = k >> 7;
  int ci = k & 127;
  int kh = g / 3;
  int kw = g - 3 * kh;
  float f = wsrc[(size_t)(co * 128 + ci) * 9 + kh * 3 + kw];
  wq2[((k >> 6) * 256 + co) * 64 + (k & 63)] = (signed char)(int)f;
  if (idx < 256) {
    scale[idx] = (float)Aq[idx] * exp2f(-(float)Nq[idx]);   // exact: A < 2^15
  }
}

// ---------------- GEMM: C[co][n,h,w] = sum_k wq[co][k] * xt[...] ----------------
// 128x128 tile, 4 waves (2x2), 4x4 frags of mfma_i32_16x16x64_i8, BK=64.
// Persistent-B: the block's 4 xt rows (h0..h0+3, 33.8 KB) are staged ONCE; every kt's
// (kh,kw) shift is a pure LDS offset (rows +8448, w +128). Only A double-buffers
// (2 loads/wave/kt, raw s_barrier + s_waitcnt vmcnt(2) pipeline).
// Bp chunk swizzle: chunk cq of (row,w) stored at slot cq ^ (w&7) -> 8 lanes per
// 4-bank group on frag reads = conflict-free. As keeps the R2 XOR swizzle.
__global__ __launch_bounds__(256) void qconv_gemm(
    const char* __restrict__ xt, const char* __restrict__ wq2,
    const float* __restrict__ bias, const float* __restrict__ scale,
    const int* __restrict__ pmin, const int* __restrict__ pmax,
    float* __restrict__ out) {
  __shared__ __align__(16) char Bp[4 * 8448];   // 33792 B: 4 xt rows, swizzled chunks
  __shared__ __align__(16) char As[2][8192];    // [buf][m=128][kk=64]

  // XCD-aware swizzle: mt pair (shared B rows) + contiguous nt range per XCD.
  int bid = blockIdx.x;        // 1792
  int xcd = bid & 7;
  int q   = bid >> 3;
  int mt  = q & 1;
  int nt  = xcd * 112 + (q >> 1);
  int n   = nt / 28;
  int ht  = nt - n * 28;
  int h0  = ht * 2;
  int m0  = mt * 128;

  int t  = threadIdx.x;
  int wv = t >> 6;
  int ln = t & 63;
  int quad = ln >> 4;
  int l16  = ln & 15;
  int wm = wv & 1, wn = wv >> 1;

  const char* wbase = wq2 + (size_t)m0 * 64;    // + kt*16384 + row*64
  const char* xb    = xt + (size_t)n * XT_N_STRIDE + (size_t)h0 * XT_H_STRIDE;

  int a_off  = (t >> 2) * 64 + (((t & 3) ^ ((t >> 3) & 3)) * 16);  // row + swizzled piece
  int ldsA   = wv * 1024;

  // ---- stage Bp (once): slot s holds global chunk (row, w, cq^(w&7)) ----
  for (int it = 0; it < 9; ++it) {
    int s = t + it * 256;
    if (s < 2112) {                     // tail: only wave 0, full 64 lanes
      int row = s / 528;
      int rr  = s - row * 528;
      int w   = rr >> 3;
      int cq  = rr & 7;
      gload16(xb + row * XT_H_STRIDE + w * 128 + ((cq ^ (w & 7)) << 4),
              Bp + it * 4096 + wv * 1024);
    }
  }
  // ---- stage A tile kt=0 into buf 0 ----
  gload16(wbase + a_off, &As[0][ldsA]);
  gload16(wbase + 4096 + a_off, &As[0][4096 + ldsA]);
  asm volatile("s_waitcnt vmcnt(0)" ::: "memory");
  asm volatile("s_barrier" ::: "memory");

  v4i acc[4][4];
#pragma unroll
  for (int i = 0; i < 4; ++i)
#pragma unroll
    for (int j = 0; j < 4; ++j) {
      v4i z = {0, 0, 0, 0};
      acc[i][j] = z;
    }

  int ca = ((quad ^ ((l16 >> 1) & 3)) * 16);    // As read swizzle

  for (int kt = 0; kt < 18; ++kt) {
    int p  = kt & 1;
    int g  = kt >> 1;
    int kh = g / 3;
    int kw = g - 3 * kh;

    asm volatile("s_barrier" ::: "memory");             // buf 1-p free to overwrite
    if (kt < 17) {
      const char* wkt = wbase + ((kt + 1) << 14);
      gload16(wkt + a_off, &As[1 - p][ldsA]);
      gload16(wkt + 4096 + a_off, &As[1 - p][4096 + ldsA]);
      asm volatile("s_waitcnt vmcnt(2)" ::: "memory");  // oldest 2 (buf p) landed
    } else {
      asm volatile("s_waitcnt vmcnt(0)" ::: "memory");
    }
    asm volatile("s_barrier" ::: "memory");             // buf p visible to all

    // B frags: spatial sl = wn*64 + j*16 + l16 -> w = j*16+l16, dh = wn
    // k chunk cq = (kt&1)*4 + quad; stored slot = cq ^ ((w+kw)&7)
    int bswz = (((p << 2) + quad) ^ ((l16 + kw) & 7)) << 4;
    const char* bbase = Bp + (wn + kh) * XT_H_STRIDE + (l16 + kw) * 128 + bswz;

    v4i a[4], b[4];
#pragma unroll
    for (int i = 0; i < 4; ++i)
      a[i] = *(const v4i*)(&As[p][(wm * 64 + i * 16 + l16) * 64 + ca]);
#pragma unroll
    for (int j = 0; j < 4; ++j)
      b[j] = *(const v4i*)(bbase + j * 2048);
#pragma unroll
    for (int i = 0; i < 4; ++i)
#pragma unroll
      for (int j = 0; j < 4; ++j)
        acc[i][j] = __builtin_amdgcn_mfma_i32_16x16x64_i8(a[i], b[j], acc[i][j], 0, 0, 0);
  }

  // epilogue: co = m0 + wm*64 + i*16 + quad*4 + r ; spatial = wn*64 + j*16 + l16
  float mn = (float)pmin[0];
  float mx = (float)pmax[0];
#pragma unroll
  for (int i = 0; i < 4; ++i) {
    int co_b = m0 + wm * 64 + i * 16 + quad * 4;
#pragma unroll
    for (int r = 0; r < 4; ++r) {
      int co = co_b + r;
      float bs = bias[co];
      float sc = scale[co];
#pragma unroll
      for (int j = 0; j < 4; ++j) {
        int sl = wn * 64 + j * 16 + l16;
        int w  = sl & 63;
        int dh = sl >> 6;
        if (w < 56) {
          float f = (float)acc[i][j][r] + bs;
          f = rintf(f * sc);                 // half-to-even, matches np.round
          f = fminf(fmaxf(f, mn), mx);
          out[(((size_t)n * 256 + co) * 56 + (h0 + dh)) * 56 + w] = f;
        }
      }
    }
  }
}

extern "C" void kernel_launch(void* const* d_in, const int* in_sizes, int n_in,
                              void* d_out, int out_size, void* d_ws, size_t ws_size,
                              hipStream_t stream) {
  const float* x  = (const float*)d_in[0];
  const float* w  = (const float*)d_in[1];
  const float* b  = (const float*)d_in[2];
  const int*   Aq = (const int*)d_in[3];
  const int*   Nq = (const int*)d_in[4];
  const int*   mn = (const int*)d_in[5];
  const int*   mx = (const int*)d_in[6];
  float* out = (float*)d_out;

  char*  xt    = (char*)d_ws;                  // 15,679,488 B
  char*  wq2   = xt + XT_BYTES;                // 294,912 B (tile layout)
  float* scale = (float*)(wq2 + WQ_BYTES);     // 1 KiB

  hipLaunchKernelGGL(xform_x, dim3(32 * 58), dim3(256), 0, stream, x, xt);
  hipLaunchKernelGGL(xform_w, dim3(1152), dim3(256), 0, stream, w, Aq, Nq, wq2, scale);
  hipLaunchKernelGGL(qconv_gemm, dim3(1792), dim3(256), 0, stream,
                     xt, wq2, b, scale, mn, mx, out);
}